// Round 4
// baseline (990.894 us; speedup 1.0000x reference)
//
#include <hip/hip_runtime.h>

// GATv2 fused: s = a·lrelu(M@W0^T + M[rev]@W1^T + b), segment softmax over dest,
// out = segsum(alpha*M). E=800000, N=50000, D=128.
// R4: pipelining attempt regressed; counters showed random 512-B row reads of M at
//     ~1.85 TB/s are the bottleneck (score 263us: Mfma 8%, VALU 16%, hbm 33%).
// R5: fp16 M copy regressed (+28us): halving random-row BYTES didn't change time ->
//     random reads are rate-limited PER ROW (~3.6-4G rows/s, one activate per row),
//     not per byte. Row count is the currency.
// R6: single fused per-node kernel. Per node n: stage [M(e_i)|M(rev_i)] rows in LDS
//     (1.6M random rows total - the irreducible set), K=256 MFMA, EXACT local softmax
//     (no global denom/atomics/pbuf), out[n] accumulated from LDS (M[e_i] NOT re-read
//     from HBM). Deletes: 0.8M-row sequential sweep, convert_m, norm pass, denom.

#define SLOPE 0.2f
constexpr int E = 800000;
constexpr int N = 50000;
constexpr int D = 128;
constexpr int LDA = 264;                // halves per A row: 256 + 8 pad (bank spread)
constexpr int MAXDEG = 64;              // Poisson(16) max-degree bound; P(overflow) ~1e-13

typedef __attribute__((ext_vector_type(8))) _Float16 f16x8;
typedef __attribute__((ext_vector_type(4))) _Float16 f16x4;
typedef __attribute__((ext_vector_type(4))) float f32x4;

// ---- K0: convert W0,W1 -> Wh[d][k] fp16, k in [0,256): [W0 row d | W1 row d]
__global__ void convert_w(const float* __restrict__ W0, const float* __restrict__ W1,
                          _Float16* __restrict__ Wh) {
    int i = blockIdx.x * blockDim.x + threadIdx.x;   // 0..32767
    if (i >= D * 256) return;
    int d = i >> 8, k = i & 255;
    float v = (k < 128) ? W0[d * 128 + k] : W1[d * 128 + (k - 128)];
    Wh[i] = (_Float16)v;                             // RNE
}

// ---- K_b: bucket edges by dest. cnt must be pre-zeroed.
__global__ void bucket_build(const int* __restrict__ dest, int* __restrict__ cnt,
                             int* __restrict__ bucket) {
    int e = blockIdx.x * blockDim.x + threadIdx.x;
    if (e >= E) return;
    int n = dest[e];
    int pos = atomicAdd(&cnt[n], 1);
    if (pos < MAXDEG) bucket[n * MAXDEG + pos] = e;
}

// ---- K1: fully fused per-node kernel. One 256-thread block (4 waves) per node.
// Wave w owns d-cols [w*32, w*32+32). acc capped at 2 i-blocks (32 rows) per pass;
// nodes with deg>32 (~2%) loop the MFMA+epilogue twice.
__global__ __launch_bounds__(256, 4) void fused_kernel(
    const float* __restrict__ M, const int* __restrict__ rev,
    const _Float16* __restrict__ Wh,
    const float* __restrict__ b0, const float* __restrict__ b1,
    const float* __restrict__ a_w, const float* __restrict__ a_b,
    const int* __restrict__ cnt, const int* __restrict__ bucket,
    float* __restrict__ out, float* __restrict__ alpha)
{
    __shared__ _Float16 Alds[MAXDEG * LDA];   // 33792 B
    __shared__ float red[4][MAXDEG];          // 1024 B
    __shared__ float alf[MAXDEG];             // 256 B
    __shared__ int ebL[MAXDEG];               // 256 B
    __shared__ int rvL[MAXDEG];               // 256 B

    const int n = blockIdx.x;
    const int t = threadIdx.x;
    const int w = t >> 6;                  // wave 0..3
    const int lane = t & 63;
    const int lo = lane & 15, hi = lane >> 4;
    const int dr = w * 32;                 // this wave's d-col base

    int c = cnt[n];
    c = (c > MAXDEG) ? MAXDEG : c;

    // ---- W fragments (K=256 concatenated [W0|W1]) resident in registers
    f16x8 b[2][8];
#pragma unroll
    for (int j = 0; j < 2; ++j) {
        int d = dr + j * 16 + lo;
#pragma unroll
        for (int ks = 0; ks < 8; ++ks)
            b[j][ks] = *(const f16x8*)(Wh + d * 256 + ks * 32 + hi * 8);
    }
    float bs[2], aw[2];
#pragma unroll
    for (int j = 0; j < 2; ++j) {
        int d = dr + j * 16 + lo;
        bs[j] = b0[d] + b1[d];
        aw[j] = a_w[d];
    }
    const float ab = a_b[0];

    // ---- index prefetch: edge ids + rev ids for this node
    if (t < MAXDEG) {
        int e = 0, rv = 0;
        if (t < c) { e = bucket[n * MAXDEG + t]; rv = rev[e]; }
        ebL[t] = e; rvL[t] = rv;
    }
    __syncthreads();

    // ---- stage: row i = [f16(M[e_i]) | f16(M[rev_i])] (random fp32 row reads)
    const int col = t & 31;    // float4 col 0..31
    const int rr  = t >> 5;    // 0..7
    for (int i0 = 0; i0 < c; i0 += 8) {
        int i = i0 + rr;
        if (i < c) {
            const float4 v = ((const float4*)(M + (size_t)ebL[i] * D))[col];
            const float4 u = ((const float4*)(M + (size_t)rvL[i] * D))[col];
            f16x4 hv = { (_Float16)v.x, (_Float16)v.y, (_Float16)v.z, (_Float16)v.w };
            f16x4 hu = { (_Float16)u.x, (_Float16)u.y, (_Float16)u.z, (_Float16)u.w };
            *(f16x4*)(Alds + i * LDA + col * 4) = hv;
            *(f16x4*)(Alds + i * LDA + 128 + col * 4) = hu;
        }
    }
    __syncthreads();

    // ---- MFMA + epilogue: X = A @ Wh^T over this wave's 32 cols, s-partials to red
    const int nb = (c + 15) >> 4;          // i-blocks of 16 rows
    for (int ib0 = 0; ib0 < nb; ib0 += 2) {
        const int nbi = (nb - ib0 < 2) ? (nb - ib0) : 2;
        const int r1 = (ib0 + 1 < nb) ? (ib0 + 1) : ib0;   // clamp A-row block (unused if nbi==1)
        f32x4 zero = {0.f, 0.f, 0.f, 0.f};
        f32x4 acc[2][2];
#pragma unroll
        for (int ii = 0; ii < 2; ++ii)
#pragma unroll
            for (int j = 0; j < 2; ++j) acc[ii][j] = zero;

#pragma unroll
        for (int ks = 0; ks < 8; ++ks) {
            f16x8 a[2];
            a[0] = *(const f16x8*)(Alds + (ib0 * 16 + lo) * LDA + ks * 32 + hi * 8);
            a[1] = *(const f16x8*)(Alds + (r1  * 16 + lo) * LDA + ks * 32 + hi * 8);
#pragma unroll
            for (int ii = 0; ii < 2; ++ii)
#pragma unroll
                for (int j = 0; j < 2; ++j)
                    acc[ii][j] = __builtin_amdgcn_mfma_f32_16x16x32_f16(a[ii], b[j][ks], acc[ii][j], 0, 0, 0);
        }

        for (int ii = 0; ii < nbi; ++ii) {
#pragma unroll
            for (int r = 0; r < 4; ++r) {
                float v = 0.f;
#pragma unroll
                for (int j = 0; j < 2; ++j) {
                    float x = acc[ii][j][r] + bs[j];
                    x = (x > 0.f) ? x : SLOPE * x;
                    v += aw[j] * x;
                }
                v += __shfl_xor(v, 1);
                v += __shfl_xor(v, 2);
                v += __shfl_xor(v, 4);
                v += __shfl_xor(v, 8);
                if (lo == 0) red[w][(ib0 + ii) * 16 + hi * 4 + r] = v;
            }
        }
    }
    __syncthreads();

    // ---- exact local softmax (wave 0 = threads 0..63)
    if (t < MAXDEG) {
        float s = (t < c) ? (red[0][t] + red[1][t] + red[2][t] + red[3][t] + ab) : -3.0e38f;
        float m = s;
#pragma unroll
        for (int off = 1; off < 64; off <<= 1) m = fmaxf(m, __shfl_xor(m, off));
        float p = (t < c) ? __expf(s - m) : 0.f;
        float dsum = p;
#pragma unroll
        for (int off = 1; off < 64; off <<= 1) dsum += __shfl_xor(dsum, off);
        float al = (t < c) ? (p / dsum) : 0.f;
        alf[t] = al;
        if (t < c) alpha[ebL[t]] = al;     // random 4B scatter, L2-absorbed (3.2MB)
    }
    __syncthreads();

    // ---- out[n] = sum_i alf[i] * M[e_i]  (M rows still in LDS, first 128 halves)
    {
        const int cl = lane & 31;          // col within this wave's 32
        const int half = lane >> 5;        // i-parity split across lane halves
        float a0 = 0.f;
        for (int i = half; i < c; i += 2)
            a0 = fmaf(alf[i], (float)Alds[i * LDA + dr + cl], a0);
        a0 += __shfl_xor(a0, 32);
        if (half == 0) out[(size_t)n * D + dr + cl] = a0;
    }
}

extern "C" void kernel_launch(void* const* d_in, const int* in_sizes, int n_in,
                              void* d_out, int out_size, void* d_ws, size_t ws_size,
                              hipStream_t stream) {
    const float* M   = (const float*)d_in[0];
    const int*   dst = (const int*)d_in[1];
    const int*   rev = (const int*)d_in[2];
    // d_in[3] = dim_size (compile-time constant N)
    const float* W0  = (const float*)d_in[4];
    const float* b0  = (const float*)d_in[5];
    const float* W1  = (const float*)d_in[6];
    const float* b1  = (const float*)d_in[7];
    const float* a_w = (const float*)d_in[8];
    const float* a_b = (const float*)d_in[9];

    float* out   = (float*)d_out;            // [N,128]
    float* alpha = out + (size_t)N * D;      // [E]

    int*       cnt    = (int*)d_ws;                      // [N]             (200000 B)
    _Float16*  Wh     = (_Float16*)(cnt + N);            // [128][256] fp16 (65536 B)
    int*       bucket = (int*)(Wh + D * 256);            // [N][MAXDEG]     (12.8 MB)

    hipMemsetAsync(cnt, 0, (size_t)N * sizeof(int), stream);

    convert_w<<<128, 256, 0, stream>>>(W0, W1, Wh);
    bucket_build<<<(E + 255) / 256, 256, 0, stream>>>(dst, cnt, bucket);
    fused_kernel<<<N, 256, 0, stream>>>(M, rev, Wh, b0, b1, a_w, a_b,
                                        cnt, bucket, out, alpha);
}